// Round 3
// baseline (359.268 us; speedup 1.0000x reference)
//
#include <hip/hip_runtime.h>
#include <cstdint>
#include <cstddef>

// Problem constants (fixed by the reference: B=8192, F=1024, N=4096)
#define B_DIM 8192
#define F_DIM 1024
#define N_DIM 4096

// R13 (resubmit x2 after broker timeouts): 256x256-tile 4-phase schedule
// (T3-minimal from the 8-phase template family). 8 waves (2M x 4N),
// 128x64 out per wave, BK=128 fp8.
// Per K-tile: stage next tile's 8 global_load_lds FIRST (front-loaded issue),
// then 4 quadrant phases {ds_read frags; setprio(1); 8 MFMA; setprio(0)},
// then ONE vmcnt(0)+s_barrier boundary (loads are ~4 phases old -> cheap).
// Provably race-free: buf^1 is only written after the boundary barrier that
// ends all reads of it; per-wave vmcnt(0)+barrier makes all slices visible.
#define BM 256
#define BN 256
#define BK 128

typedef float floatx4 __attribute__((ext_vector_type(4)));
typedef int intx4 __attribute__((ext_vector_type(4)));
typedef int intx8 __attribute__((ext_vector_type(8)));

typedef const __attribute__((address_space(1))) unsigned int* as1_u32cp;
typedef __attribute__((address_space(3))) unsigned int* as3_u32p;

// Async global->LDS 16B copy. LDS dest is wave-uniform base + lane*16.
__device__ __forceinline__ void gload_lds16(const uint8_t* g, uint8_t* l) {
    __builtin_amdgcn_global_load_lds((as1_u32cp)(const unsigned int*)g,
                                     (as3_u32p)(unsigned int*)l, 16, 0, 0);
}

__device__ __forceinline__ float hardswish_f(float l) {
    float g = fminf(fmaxf(l + 3.0f, 0.0f), 6.0f);
    return l * g * (1.0f / 6.0f);
}

// fp32 -> fp8 e4m3 for x|y|w (dst contiguous in ws) + rowsum-zero tail.
__global__ __launch_bounds__(256) void k_cvt(
    const float* __restrict__ x, const float* __restrict__ y,
    const float* __restrict__ wt, uint8_t* __restrict__ dst,
    float* __restrict__ rowsum, int n4x, int n4w) {
    int i = blockIdx.x * 256 + threadIdx.x;
    int total = 2 * n4x + n4w;
    if (i >= total) {
        int r = i - total;
        if (r < B_DIM / 4) ((float4*)rowsum)[r] = make_float4(0.f, 0.f, 0.f, 0.f);
        return;
    }
    const float* src;
    int j;
    if (i < n4x) { src = x; j = i; }
    else if (i < 2 * n4x) { src = y; j = i - n4x; }
    else { src = wt; j = i - 2 * n4x; }
    float4 v = ((const float4*)src)[j];
    int p = __builtin_amdgcn_cvt_pk_fp8_f32(v.x, v.y, 0, false);
    p = __builtin_amdgcn_cvt_pk_fp8_f32(v.z, v.w, p, true);
    ((int*)dst)[i] = p;
}

// C = A * B^T, A[M][K], Bm[N][K] row-major fp8 e4m3, fp32 accumulate via
// mfma_scale_f32_16x16x128_f8f6f4 with unit scales (E8M0 0x7F = 2^0).
// LDS XOR-swizzled in 16B chunks: slot (row,s) holds global chunk s^(row&7).
// A-fragment (16x16x128): row=lane&15, k = quad*32 + reg*4 + byte
// -> 32 contiguous bytes = swizzled slots {(2q)^e, (2q+1)^e}, e=row&7.
// C/D layout: col=lane&15, row=quad*4+reg.
// MODE 1: epilogue sums exp(C[i][j]) into rowsum[i] (scores never hit HBM).
// MODE 2: prologue addv[256]=hardswish(log(rowsum)); epilogue transposed
//         through LDS (stride 260 floats) in 4 passes of 64 rows for
//         coalesced float4 stores of out = clamp(C + bias + addv, -1, 1).
template <int MODE>
__device__ __forceinline__ void gemm_body(
    const uint8_t* __restrict__ A,
    const uint8_t* __restrict__ Bm,
    int K, int N,
    float* __restrict__ rowsum,
    const float* __restrict__ bias,
    float* __restrict__ out) {
    // 128 KB staging (2 bufs x (A 32KB | B 32KB)); MODE 2 reuses it as epi.
    __shared__ __align__(16) uint8_t smem[2][2][BM * BK];
    __shared__ float addv[BM];  // separate: must not alias epi

    const int t = threadIdx.x;   // 0..511
    const int lane = t & 63;
    const int w = t >> 6;        // 0..7
    const int quad = lane >> 4;  // 0..3
    const int lc = lane & 15;    // 0..15
    const int wm = w >> 2;       // 0..1 : which 128-row half
    const int wn = w & 3;        // 0..3 : which 64-col quarter
    const int rowBase = blockIdx.y * BM;
    const int colBase = blockIdx.x * BN;

    // Precompute staging addresses: 4 chunks/tensor, 16B/lane, 8 KB/instr.
    const uint8_t* gA[4];
    const uint8_t* gB[4];
    int ldsOff[4];
#pragma unroll
    for (int c = 0; c < 4; ++c) {
        const int idx = c * 512 + t;   // chunk slot 0..2047
        const int row = idx >> 3;      // 0..255
        const int cg = (idx & 7) ^ (row & 7);
        gA[c] = A + (size_t)(rowBase + row) * K + cg * 16;
        gB[c] = Bm + (size_t)(colBase + row) * K + cg * 16;
        ldsOff[c] = idx * 16;
    }

    if constexpr (MODE == 2) {
        // one log per thread; consumed only after epilogue __syncthreads()
        if (t < BM) addv[t] = hardswish_f(logf(rowsum[rowBase + t]));
    }

    floatx4 acc[8][4];
#pragma unroll
    for (int mi = 0; mi < 8; ++mi)
#pragma unroll
        for (int ni = 0; ni < 4; ++ni)
            acc[mi][ni] = (floatx4){0.f, 0.f, 0.f, 0.f};

    auto stage = [&](int kt) {
        uint8_t* la = &smem[kt & 1][0][0];
        uint8_t* lb = &smem[kt & 1][1][0];
        const int ko = kt * BK;
#pragma unroll
        for (int c = 0; c < 4; ++c) {
            gload_lds16(gA[c] + ko, la + ldsOff[c]);
            gload_lds16(gB[c] + ko, lb + ldsOff[c]);
        }
    };

    auto rdA = [&](intx8 (&af)[4], const uint8_t* As, int r0) {
#pragma unroll
        for (int mi = 0; mi < 4; ++mi) {
            const int row = r0 + mi * 16 + lc;
            const int e = row & 7;
            ((intx4*)&af[mi])[0] = *(const intx4*)(As + row * BK + ((2 * quad) ^ e) * 16);
            ((intx4*)&af[mi])[1] = *(const intx4*)(As + row * BK + ((2 * quad + 1) ^ e) * 16);
        }
    };
    auto rdB = [&](intx8 (&bf)[2], const uint8_t* Bs, int r0) {
#pragma unroll
        for (int ni = 0; ni < 2; ++ni) {
            const int row = r0 + ni * 16 + lc;
            const int e = row & 7;
            ((intx4*)&bf[ni])[0] = *(const intx4*)(Bs + row * BK + ((2 * quad) ^ e) * 16);
            ((intx4*)&bf[ni])[1] = *(const intx4*)(Bs + row * BK + ((2 * quad + 1) ^ e) * 16);
        }
    };
    auto mma2x4 = [&](intx8 (&af)[4], intx8 (&bf)[2], int miH, int niH) {
#pragma unroll
        for (int mi = 0; mi < 4; ++mi)
#pragma unroll
            for (int ni = 0; ni < 2; ++ni)
                acc[miH * 4 + mi][niH * 2 + ni] =
                    __builtin_amdgcn_mfma_scale_f32_16x16x128_f8f6f4(
                        af[mi], bf[ni], acc[miH * 4 + mi][niH * 2 + ni],
                        0, 0,                // cbsz=fp8(e4m3), blgp=fp8(e4m3)
                        0, 0x7F7F7F7F,       // A scale: 1.0
                        0, 0x7F7F7F7F);      // B scale: 1.0
    };

    // Prologue: stage tile 0, hard wait once.
    stage(0);
    asm volatile("s_waitcnt vmcnt(0)" ::: "memory");
    __builtin_amdgcn_s_barrier();
    asm volatile("" ::: "memory");

    const int nIter = K / BK;
    for (int kt = 0; kt < nIter; ++kt) {
        const uint8_t* As = &smem[kt & 1][0][0];
        const uint8_t* Bs = &smem[kt & 1][1][0];
        // Front-loaded issue: next tile's loads fly under this tile's MFMA.
        if (kt + 1 < nIter) stage(kt + 1);

        intx8 af[4], bf[2];
        // phase 1: quadrant (0,0) — fresh A-lo + B-lo
        rdA(af, As, wm * 128);
        rdB(bf, Bs, wn * 64);
        __builtin_amdgcn_s_setprio(1);
        mma2x4(af, bf, 0, 0);
        __builtin_amdgcn_s_setprio(0);
        __builtin_amdgcn_sched_barrier(0);
        // phase 2: quadrant (0,1) — reuse A-lo, fresh B-hi
        rdB(bf, Bs, wn * 64 + 32);
        __builtin_amdgcn_s_setprio(1);
        mma2x4(af, bf, 0, 1);
        __builtin_amdgcn_s_setprio(0);
        __builtin_amdgcn_sched_barrier(0);
        // phase 3: quadrant (1,1) — fresh A-hi, reuse B-hi
        rdA(af, As, wm * 128 + 64);
        __builtin_amdgcn_s_setprio(1);
        mma2x4(af, bf, 1, 1);
        __builtin_amdgcn_s_setprio(0);
        __builtin_amdgcn_sched_barrier(0);
        // phase 4: quadrant (1,0) — reuse A-hi, fresh B-lo
        rdB(bf, Bs, wn * 64);
        __builtin_amdgcn_s_setprio(1);
        mma2x4(af, bf, 1, 0);
        __builtin_amdgcn_s_setprio(0);

        // Tile boundary: next tile's loads are ~4 phases old -> near-free
        // drain; barrier publishes every wave's slices before any read.
        asm volatile("s_waitcnt vmcnt(0)" ::: "memory");
        __builtin_amdgcn_s_barrier();
        asm volatile("" ::: "memory");
    }

    if constexpr (MODE == 1) {
        // sum exp over this wave's 64 columns for each of its 128 rows
#pragma unroll
        for (int mi = 0; mi < 8; ++mi) {
#pragma unroll
            for (int r = 0; r < 4; ++r) {
                float p = 0.f;
#pragma unroll
                for (int ni = 0; ni < 4; ++ni) p += __expf(acc[mi][ni][r]);
                // butterfly over the 16 columns held by this quad's 16 lanes
                p += __shfl_xor(p, 1, 16);
                p += __shfl_xor(p, 2, 16);
                p += __shfl_xor(p, 4, 16);
                p += __shfl_xor(p, 8, 16);
                if (lc == 0) {
                    int row = rowBase + wm * 128 + mi * 16 + quad * 4 + r;
                    atomicAdd(&rowsum[row], p);
                }
            }
        }
    } else {
        float bv[4];
#pragma unroll
        for (int ni = 0; ni < 4; ++ni)
            bv[ni] = bias[colBase + wn * 64 + ni * 16 + lc];
        float* epi = (float*)smem;
        __syncthreads();  // all K-loop LDS reads done before reuse
        // 4 passes of 64 rows: owning waves dump (bias+addv+clamp)ed tiles
        // into epi[64][260], then all 512 threads store coalesced float4.
#pragma unroll
        for (int h = 0; h < 4; ++h) {
            if (wm == (h >> 1)) {
                const int mi0 = (h & 1) * 4;
#pragma unroll
                for (int mi = 0; mi < 4; ++mi) {
                    const int lr0 = mi * 16 + quad * 4;  // local row 0..60
#pragma unroll
                    for (int ni = 0; ni < 4; ++ni) {
                        const int c = wn * 64 + ni * 16 + lc;
#pragma unroll
                        for (int r = 0; r < 4; ++r) {
                            float v = acc[mi0 + mi][ni][r] + bv[ni] + addv[h * 64 + lr0 + r];
                            v = fminf(fmaxf(v, -1.0f), 1.0f);
                            epi[(lr0 + r) * 260 + c] = v;
                        }
                    }
                }
            }
            __syncthreads();  // epi visible to all
#pragma unroll
            for (int k = 0; k < 8; ++k) {
                const int idx = k * 512 + t;   // 0..4095
                const int row = idx >> 6;      // 0..63
                const int c4 = (idx & 63) * 4; // 0..252
                float4 v = *(const float4*)&epi[row * 260 + c4];
                *(float4*)&out[(size_t)(rowBase + h * 64 + row) * N + colBase + c4] = v;
            }
            __syncthreads();  // epi free for next pass
        }
    }
}

__global__ __launch_bounds__(512, 2) void k_g1(
    const uint8_t* __restrict__ A, const uint8_t* __restrict__ Bm,
    int K, int N, float* __restrict__ rowsum) {
    gemm_body<1>(A, Bm, K, N, rowsum, nullptr, nullptr);
}

__global__ __launch_bounds__(512, 2) void k_g2(
    const uint8_t* __restrict__ A, const uint8_t* __restrict__ Bm,
    int K, int N, float* __restrict__ rowsum,
    const float* __restrict__ bias, float* __restrict__ out) {
    gemm_body<2>(A, Bm, K, N, rowsum, bias, out);
}

extern "C" void kernel_launch(void* const* d_in, const int* in_sizes, int n_in,
                              void* d_out, int out_size, void* d_ws, size_t ws_size,
                              hipStream_t stream) {
    const float* x = (const float*)d_in[0];     // [B, F]
    const float* y = (const float*)d_in[1];     // [B, F]
    const float* wt = (const float*)d_in[2];    // [N, F]
    const float* bias = (const float*)d_in[3];  // [N]
    float* out = (float*)d_out;                 // [B, N]

    // Workspace: xq 8MB | yq 8MB | wq 4MB | rowsum 32KB (contiguous fp8 dst)
    uint8_t* xq = (uint8_t*)d_ws;
    uint8_t* yq = xq + (size_t)B_DIM * F_DIM;
    uint8_t* wq = yq + (size_t)B_DIM * F_DIM;
    float* rowsum = (float*)(wq + (size_t)N_DIM * F_DIM);

    const int n4_x = B_DIM * F_DIM / 4;
    const int n4_w = N_DIM * F_DIM / 4;
    const int total_thr = 2 * n4_x + n4_w + B_DIM / 4;  // cvt + rowsum-zero tail
    k_cvt<<<(total_thr + 255) / 256, 256, 0, stream>>>(
        x, y, wt, xq, rowsum, n4_x, n4_w);

    // Stage 1: scores = x . y^T, fused exp-rowsum
    k_g1<<<dim3(B_DIM / BN, B_DIM / BM), 512, 0, stream>>>(
        xq, yq, F_DIM, B_DIM, rowsum);

    // Stage 2: out = y . w^T + bias + hardswish(log(rowsum)), clamped
    k_g2<<<dim3(N_DIM / BN, B_DIM / BM), 512, 0, stream>>>(
        yq, wq, F_DIM, N_DIM, rowsum, bias, out);
}